// Round 8
// baseline (472.868 us; speedup 1.0000x reference)
//
#include <hip/hip_runtime.h>
#include <hip/hip_bf16.h>

#define N_NODES 150000
#define M_HYPER 50000
#define N_TOTAL 200000
#define DIM 64
#define NCLASS 50
#define NNZ 3200000

#define BSHIFT 9
#define BROWS 512
#define NBUK ((N_TOTAL + BROWS - 1) / BROWS)  // 391
#define EB 8192                               // edges per binning block

// ---------------------------------------------------------------------------
// Phase A0: coarse bucket histogram (LDS-aggregated)
// ---------------------------------------------------------------------------
__global__ __launch_bounds__(256) void bucket_hist(const int* __restrict__ rows,
                                                   int* __restrict__ bcnt) {
    __shared__ int h[NBUK];
    for (int i = threadIdx.x; i < NBUK; i += 256) h[i] = 0;
    __syncthreads();
    int base = blockIdx.x * EB;
    int cntE = NNZ - base; if (cntE > EB) cntE = EB;
    for (int i = threadIdx.x; i < cntE; i += 256)
        atomicAdd(&h[rows[base + i] >> BSHIFT], 1);
    __syncthreads();
    for (int i = threadIdx.x; i < NBUK; i += 256) {
        int v = h[i];
        if (v) atomicAdd(&bcnt[i], v);
    }
}

// ---------------------------------------------------------------------------
// Phase A0s: exclusive scan over 391 bucket counts (single block)
// ---------------------------------------------------------------------------
__global__ __launch_bounds__(512) void bucket_scan(const int* __restrict__ bcnt,
                                                   int* __restrict__ boff,
                                                   int* __restrict__ bcur) {
    __shared__ int sh[512];
    int t = threadIdx.x;
    sh[t] = (t < NBUK) ? bcnt[t] : 0;
    __syncthreads();
    for (int off = 1; off < 512; off <<= 1) {
        int v = (t >= off) ? sh[t - off] : 0;
        __syncthreads();
        sh[t] += v;
        __syncthreads();
    }
    if (t < NBUK) {
        int ex = (t == 0) ? 0 : sh[t - 1];
        boff[t] = ex;
        bcur[t] = ex;
    }
    if (t == 0) boff[NBUK] = NNZ;
}

// ---------------------------------------------------------------------------
// Phase A1: bin edges into bucket regions with per-block LDS aggregation.
// rec.x = (rrel << 18) | col, rec.y = f32 val bits
// ---------------------------------------------------------------------------
__global__ __launch_bounds__(256) void bin_edges(
    const int* __restrict__ rows, const int* __restrict__ cols,
    const float* __restrict__ vals, int* __restrict__ bcur,
    int2* __restrict__ recs) {
    __shared__ int h[NBUK];
    __shared__ int lbase[NBUK];
    int base = blockIdx.x * EB;
    int cntE = NNZ - base; if (cntE > EB) cntE = EB;
    for (int i = threadIdx.x; i < NBUK; i += 256) h[i] = 0;
    __syncthreads();
    for (int i = threadIdx.x; i < cntE; i += 256)
        atomicAdd(&h[rows[base + i] >> BSHIFT], 1);
    __syncthreads();
    for (int i = threadIdx.x; i < NBUK; i += 256) {
        int c = h[i];
        lbase[i] = c ? atomicAdd(&bcur[i], c) : 0;
    }
    __syncthreads();
    for (int i = threadIdx.x; i < NBUK; i += 256) h[i] = 0;
    __syncthreads();
    for (int i = threadIdx.x; i < cntE; i += 256) {
        int e = base + i;
        int r = rows[e];
        int b = r >> BSHIFT;
        int p = lbase[b] + atomicAdd(&h[b], 1);
        recs[p] = make_int2(((r & (BROWS - 1)) << 18) | cols[e],
                            __float_as_int(vals[e]));
    }
}

// ---------------------------------------------------------------------------
// Phase B: per-bucket exact CSR build. One workgroup per bucket.
// ---------------------------------------------------------------------------
__global__ __launch_bounds__(256) void build_csr(const int* __restrict__ boff,
                                                 const int2* __restrict__ recs,
                                                 int* __restrict__ row_ptr,
                                                 int2* __restrict__ edges) {
    __shared__ int h[BROWS];
    __shared__ int ex[BROWS];
    __shared__ int ps[256];
    int b = blockIdx.x, t = threadIdx.x;
    int base = boff[b];
    int cnt = boff[b + 1] - base;
    int row0 = b << BSHIFT;
    int nrows = N_TOTAL - row0;
    if (nrows > BROWS) nrows = BROWS;
    h[t] = 0;
    h[t + 256] = 0;
    __syncthreads();
    for (int i = t; i < cnt; i += 256)
        atomicAdd(&h[recs[base + i].x >> 18], 1);
    __syncthreads();
    int a0 = h[2 * t], a1 = h[2 * t + 1];
    ps[t] = a0 + a1;
    __syncthreads();
    for (int off = 1; off < 256; off <<= 1) {
        int v = (t >= off) ? ps[t - off] : 0;
        __syncthreads();
        ps[t] += v;
        __syncthreads();
    }
    int e0 = (t == 0) ? 0 : ps[t - 1];
    ex[2 * t] = e0;
    ex[2 * t + 1] = e0 + a0;
    __syncthreads();
    for (int i = t; i < nrows; i += 256) row_ptr[row0 + i] = base + ex[i];
    if (b == NBUK - 1 && t == 0) row_ptr[N_TOTAL] = NNZ;
    h[t] = base + ex[t];
    h[t + 256] = base + ex[t + 256];
    __syncthreads();
    for (int i = t; i < cnt; i += 256) {
        int2 rc = recs[base + i];
        int p = atomicAdd(&h[rc.x >> 18], 1);
        edges[p] = make_int2(rc.x & 0x3FFFF, rc.y);
    }
}

// ---------------------------------------------------------------------------
// Build bf16 all_emb from f32 node_emb / hyper_emb. 4 elems per thread.
// ---------------------------------------------------------------------------
__global__ __launch_bounds__(256) void build_x_bf16(
    const float* __restrict__ node_emb, const float* __restrict__ hyper_emb,
    __hip_bfloat162* __restrict__ xb) {
    int i = blockIdx.x * 256 + threadIdx.x;
    size_t base = (size_t)i * 4;
    const size_t NN = (size_t)N_NODES * DIM;
    if (base >= (size_t)N_TOTAL * DIM) return;
    float4 f;
    if (base < NN)
        f = *reinterpret_cast<const float4*>(node_emb + base);
    else
        f = *reinterpret_cast<const float4*>(hyper_emb + (base - NN));
    xb[2 * i] = __float22bfloat162_rn(make_float2(f.x, f.y));
    xb[2 * i + 1] = __float22bfloat162_rn(make_float2(f.z, f.w));
}

// ---------------------------------------------------------------------------
// SpMM gather: 32 lanes per row (lane = 2 dims via ushort2), 2 rows per wave,
// unroll x4 per row.
// ---------------------------------------------------------------------------
__device__ __forceinline__ float2 bf2_to_f2(unsigned g) {
    float2 r;
    r.x = __uint_as_float(g << 16);
    r.y = __uint_as_float(g & 0xffff0000u);
    return r;
}

__global__ __launch_bounds__(256) void spmm_gather(
    const int* __restrict__ row_ptr, const int2* __restrict__ edges,
    const unsigned short* __restrict__ x, unsigned short* __restrict__ y,
    int nrows) {
    int gid = blockIdx.x * 256 + threadIdx.x;
    int row = gid >> 5;
    int lane = threadIdx.x & 31;
    if (row >= nrows) return;
    int beg = row_ptr[row], end = row_ptr[row + 1];
    float rx = 0.f, ry = 0.f;
    int k = beg;
    for (; k + 3 < end; k += 4) {
        int2 e0 = edges[k], e1 = edges[k + 1], e2 = edges[k + 2],
             e3 = edges[k + 3];
        unsigned g0 = *(const unsigned*)(x + ((size_t)e0.x << 6) + lane * 2);
        unsigned g1 = *(const unsigned*)(x + ((size_t)e1.x << 6) + lane * 2);
        unsigned g2 = *(const unsigned*)(x + ((size_t)e2.x << 6) + lane * 2);
        unsigned g3 = *(const unsigned*)(x + ((size_t)e3.x << 6) + lane * 2);
        float2 f0 = bf2_to_f2(g0), f1 = bf2_to_f2(g1), f2 = bf2_to_f2(g2),
               f3 = bf2_to_f2(g3);
        float v0 = __int_as_float(e0.y), v1 = __int_as_float(e1.y);
        float v2 = __int_as_float(e2.y), v3 = __int_as_float(e3.y);
        rx = fmaf(v0, f0.x, rx); ry = fmaf(v0, f0.y, ry);
        rx = fmaf(v1, f1.x, rx); ry = fmaf(v1, f1.y, ry);
        rx = fmaf(v2, f2.x, rx); ry = fmaf(v2, f2.y, ry);
        rx = fmaf(v3, f3.x, rx); ry = fmaf(v3, f3.y, ry);
    }
    for (; k < end; ++k) {
        int2 e = edges[k];
        unsigned g = *(const unsigned*)(x + ((size_t)e.x << 6) + lane * 2);
        float2 f = bf2_to_f2(g);
        float v = __int_as_float(e.y);
        rx = fmaf(v, f.x, rx); ry = fmaf(v, f.y, ry);
    }
    __hip_bfloat162 pk = __float22bfloat162_rn(make_float2(rx, ry));
    *(unsigned*)(y + ((size_t)row << 6) + lane * 2) =
        *reinterpret_cast<unsigned*>(&pk);
}

// ---------------------------------------------------------------------------
// Fused classifier: Z = log_softmax((node_emb + y1 + y2 + y3)/4 @ W + b)
// No per-thread z array: online-softmax pass + recompute-write pass.
// Only xr[64] (constant-indexed after unroll) must live in registers.
// ---------------------------------------------------------------------------
__global__ __launch_bounds__(256) void classify(
    const float* __restrict__ node_emb, const unsigned short* __restrict__ y1,
    const unsigned short* __restrict__ y2,
    const unsigned short* __restrict__ y3, const float* __restrict__ W,
    const float* __restrict__ bias, float* __restrict__ Z) {
    __shared__ float Ws[DIM * NCLASS];
    __shared__ float bs[NCLASS];
    for (int i = threadIdx.x; i < DIM * NCLASS; i += 256) Ws[i] = W[i];
    if (threadIdx.x < NCLASS) bs[threadIdx.x] = bias[threadIdx.x];
    __syncthreads();
    int row = blockIdx.x * 256 + threadIdx.x;
    if (row >= N_NODES) return;
    const float4* np =
        reinterpret_cast<const float4*>(node_emb + (size_t)row * DIM);
    const unsigned* p1 = (const unsigned*)(y1 + ((size_t)row << 6));
    const unsigned* p2 = (const unsigned*)(y2 + ((size_t)row << 6));
    const unsigned* p3 = (const unsigned*)(y3 + ((size_t)row << 6));
    float xr[DIM];
#pragma unroll
    for (int i = 0; i < DIM / 4; ++i) {
        float4 f = np[i];
        float2 a0 = bf2_to_f2(p1[2 * i]), a1 = bf2_to_f2(p1[2 * i + 1]);
        float2 c0 = bf2_to_f2(p2[2 * i]), c1 = bf2_to_f2(p2[2 * i + 1]);
        float2 d0 = bf2_to_f2(p3[2 * i]), d1 = bf2_to_f2(p3[2 * i + 1]);
        xr[4 * i + 0] = (f.x + a0.x + c0.x + d0.x) * 0.25f;
        xr[4 * i + 1] = (f.y + a0.y + c0.y + d0.y) * 0.25f;
        xr[4 * i + 2] = (f.z + a1.x + c1.x + d1.x) * 0.25f;
        xr[4 * i + 3] = (f.w + a1.y + c1.y + d1.y) * 0.25f;
    }
    float m = -1e30f, s = 0.f;
#pragma unroll 1
    for (int c = 0; c < NCLASS; ++c) {
        float d = bs[c];
#pragma unroll
        for (int k = 0; k < DIM; ++k) d = fmaf(xr[k], Ws[k * NCLASS + c], d);
        float mn = fmaxf(m, d);
        s = s * __expf(m - mn) + __expf(d - mn);
        m = mn;
    }
    float ls = m + __logf(s);
    float* zp = Z + (size_t)row * NCLASS;
#pragma unroll 1
    for (int c = 0; c < NCLASS; ++c) {
        float d = bs[c];
#pragma unroll
        for (int k = 0; k < DIM; ++k) d = fmaf(xr[k], Ws[k * NCLASS + c], d);
        zp[c] = d - ls;
    }
}

extern "C" void kernel_launch(void* const* d_in, const int* in_sizes, int n_in,
                              void* d_out, int out_size, void* d_ws, size_t ws_size,
                              hipStream_t stream) {
    const float* node_emb = (const float*)d_in[0];
    const float* hyper_emb = (const float*)d_in[1];
    const float* W = (const float*)d_in[2];
    const float* b = (const float*)d_in[3];
    const float* vals = (const float*)d_in[4];
    const int* rows = (const int*)d_in[5];
    const int* cols = (const int*)d_in[6];
    float* Z = (float*)d_out;

    const size_t BUFB = (size_t)N_TOTAL * DIM * 2;  // 25.6 MB (bf16)
    const size_t EDG = (size_t)NNZ * 8;             // 25.6 MB (int2)

    char* w = (char*)d_ws;
    unsigned short* xb = (unsigned short*)w;  w += BUFB;
    unsigned short* y1 = (unsigned short*)w;  w += BUFB;
    unsigned short* y2 = (unsigned short*)w;  w += BUFB;
    unsigned short* y3 = (unsigned short*)w;  w += BUFB;
    int2* edges = (int2*)w;                   w += EDG;
    int* row_ptr = (int*)w;                   w += (size_t)(N_TOTAL + 1) * 4;
    int* bcnt = (int*)w;                      w += 2048;
    int* boff = (int*)w;                      w += 2048;
    int* bcur = (int*)w;
    // recs aliases y2+y3 (51.2 MB >= 25.6 MB); recs is dead before pass 2.
    int2* recs = (int2*)y2;

    // ---- Bucketed CSR build ----
    hipMemsetAsync(bcnt, 0, NBUK * 4, stream);
    const int bin_blocks = (NNZ + EB - 1) / EB;  // 391
    bucket_hist<<<bin_blocks, 256, 0, stream>>>(rows, bcnt);
    bucket_scan<<<1, 512, 0, stream>>>(bcnt, boff, bcur);
    bin_edges<<<bin_blocks, 256, 0, stream>>>(rows, cols, vals, bcur, recs);
    build_csr<<<NBUK, 256, 0, stream>>>(boff, recs, row_ptr, edges);

    // ---- Build bf16 all_emb ----
    const int cvt_blocks = (int)(((size_t)N_TOTAL * DIM / 4 + 255) / 256);
    build_x_bf16<<<cvt_blocks, 256, 0, stream>>>(node_emb, hyper_emb,
                                                 (__hip_bfloat162*)xb);

    const int out_blocks = (N_NODES + 255) / 256;
    const int full_blocks = (N_TOTAL * 32 + 255) / 256;
    const int node_blocks = (N_NODES * 32 + 255) / 256;

    // L1: y1 = A x
    spmm_gather<<<full_blocks, 256, 0, stream>>>(row_ptr, edges, xb, y1,
                                                 N_TOTAL);
    // L2: y2 = A y1
    spmm_gather<<<full_blocks, 256, 0, stream>>>(row_ptr, edges, y1, y2,
                                                 N_TOTAL);
    // L3: y3 = A y2 (node rows only)
    spmm_gather<<<node_blocks, 256, 0, stream>>>(row_ptr, edges, y2, y3,
                                                 N_NODES);
    classify<<<out_blocks, 256, 0, stream>>>(node_emb, y1, y2, y3, W, b, Z);
}

// Round 9
// 409.561 us; speedup vs baseline: 1.1546x; 1.1546x over previous
//
#include <hip/hip_runtime.h>
#include <hip/hip_bf16.h>

#define N_NODES 150000
#define M_HYPER 50000
#define N_TOTAL 200000
#define DIM 64
#define NCLASS 50
#define NNZ 3200000

#define BSHIFT 9
#define BROWS 512
#define NBUK ((N_TOTAL + BROWS - 1) / BROWS)  // 391
#define EB 8192                               // edges per binning block

// ---------------------------------------------------------------------------
// Phase A0: coarse bucket histogram (LDS-aggregated)
// ---------------------------------------------------------------------------
__global__ __launch_bounds__(256) void bucket_hist(const int* __restrict__ rows,
                                                   int* __restrict__ bcnt) {
    __shared__ int h[NBUK];
    for (int i = threadIdx.x; i < NBUK; i += 256) h[i] = 0;
    __syncthreads();
    int base = blockIdx.x * EB;
    int cntE = NNZ - base; if (cntE > EB) cntE = EB;
    for (int i = threadIdx.x; i < cntE; i += 256)
        atomicAdd(&h[rows[base + i] >> BSHIFT], 1);
    __syncthreads();
    for (int i = threadIdx.x; i < NBUK; i += 256) {
        int v = h[i];
        if (v) atomicAdd(&bcnt[i], v);
    }
}

// ---------------------------------------------------------------------------
// Phase A0s: exclusive scan over 391 bucket counts (single block)
// ---------------------------------------------------------------------------
__global__ __launch_bounds__(512) void bucket_scan(const int* __restrict__ bcnt,
                                                   int* __restrict__ boff,
                                                   int* __restrict__ bcur) {
    __shared__ int sh[512];
    int t = threadIdx.x;
    sh[t] = (t < NBUK) ? bcnt[t] : 0;
    __syncthreads();
    for (int off = 1; off < 512; off <<= 1) {
        int v = (t >= off) ? sh[t - off] : 0;
        __syncthreads();
        sh[t] += v;
        __syncthreads();
    }
    if (t < NBUK) {
        int ex = (t == 0) ? 0 : sh[t - 1];
        boff[t] = ex;
        bcur[t] = ex;
    }
    if (t == 0) boff[NBUK] = NNZ;
}

// ---------------------------------------------------------------------------
// Phase A1: bin edges into bucket regions with per-block LDS aggregation.
// rec.x = (rrel << 18) | col, rec.y = f32 val bits
// ---------------------------------------------------------------------------
__global__ __launch_bounds__(256) void bin_edges(
    const int* __restrict__ rows, const int* __restrict__ cols,
    const float* __restrict__ vals, int* __restrict__ bcur,
    int2* __restrict__ recs) {
    __shared__ int h[NBUK];
    __shared__ int lbase[NBUK];
    int base = blockIdx.x * EB;
    int cntE = NNZ - base; if (cntE > EB) cntE = EB;
    for (int i = threadIdx.x; i < NBUK; i += 256) h[i] = 0;
    __syncthreads();
    for (int i = threadIdx.x; i < cntE; i += 256)
        atomicAdd(&h[rows[base + i] >> BSHIFT], 1);
    __syncthreads();
    for (int i = threadIdx.x; i < NBUK; i += 256) {
        int c = h[i];
        lbase[i] = c ? atomicAdd(&bcur[i], c) : 0;
    }
    __syncthreads();
    for (int i = threadIdx.x; i < NBUK; i += 256) h[i] = 0;
    __syncthreads();
    for (int i = threadIdx.x; i < cntE; i += 256) {
        int e = base + i;
        int r = rows[e];
        int b = r >> BSHIFT;
        int p = lbase[b] + atomicAdd(&h[b], 1);
        recs[p] = make_int2(((r & (BROWS - 1)) << 18) | cols[e],
                            __float_as_int(vals[e]));
    }
}

// ---------------------------------------------------------------------------
// Phase B: per-bucket exact CSR build. One workgroup per bucket.
// ---------------------------------------------------------------------------
__global__ __launch_bounds__(256) void build_csr(const int* __restrict__ boff,
                                                 const int2* __restrict__ recs,
                                                 int* __restrict__ row_ptr,
                                                 int2* __restrict__ edges) {
    __shared__ int h[BROWS];
    __shared__ int ex[BROWS];
    __shared__ int ps[256];
    int b = blockIdx.x, t = threadIdx.x;
    int base = boff[b];
    int cnt = boff[b + 1] - base;
    int row0 = b << BSHIFT;
    int nrows = N_TOTAL - row0;
    if (nrows > BROWS) nrows = BROWS;
    h[t] = 0;
    h[t + 256] = 0;
    __syncthreads();
    for (int i = t; i < cnt; i += 256)
        atomicAdd(&h[recs[base + i].x >> 18], 1);
    __syncthreads();
    int a0 = h[2 * t], a1 = h[2 * t + 1];
    ps[t] = a0 + a1;
    __syncthreads();
    for (int off = 1; off < 256; off <<= 1) {
        int v = (t >= off) ? ps[t - off] : 0;
        __syncthreads();
        ps[t] += v;
        __syncthreads();
    }
    int e0 = (t == 0) ? 0 : ps[t - 1];
    ex[2 * t] = e0;
    ex[2 * t + 1] = e0 + a0;
    __syncthreads();
    for (int i = t; i < nrows; i += 256) row_ptr[row0 + i] = base + ex[i];
    if (b == NBUK - 1 && t == 0) row_ptr[N_TOTAL] = NNZ;
    h[t] = base + ex[t];
    h[t + 256] = base + ex[t + 256];
    __syncthreads();
    for (int i = t; i < cnt; i += 256) {
        int2 rc = recs[base + i];
        int p = atomicAdd(&h[rc.x >> 18], 1);
        edges[p] = make_int2(rc.x & 0x3FFFF, rc.y);
    }
}

// ---------------------------------------------------------------------------
// Build bf16 all_emb from f32 node_emb / hyper_emb. 4 elems per thread.
// ---------------------------------------------------------------------------
__global__ __launch_bounds__(256) void build_x_bf16(
    const float* __restrict__ node_emb, const float* __restrict__ hyper_emb,
    __hip_bfloat162* __restrict__ xb) {
    int i = blockIdx.x * 256 + threadIdx.x;
    size_t base = (size_t)i * 4;
    const size_t NN = (size_t)N_NODES * DIM;
    if (base >= (size_t)N_TOTAL * DIM) return;
    float4 f;
    if (base < NN)
        f = *reinterpret_cast<const float4*>(node_emb + base);
    else
        f = *reinterpret_cast<const float4*>(hyper_emb + (base - NN));
    xb[2 * i] = __float22bfloat162_rn(make_float2(f.x, f.y));
    xb[2 * i + 1] = __float22bfloat162_rn(make_float2(f.z, f.w));
}

// ---------------------------------------------------------------------------
// SpMM gather: 32 lanes per row (lane = 2 dims via ushort2), 2 rows per wave,
// unroll x8 per row -> up to 8 outstanding gathers per half-wave.
// ---------------------------------------------------------------------------
__device__ __forceinline__ float2 bf2_to_f2(unsigned g) {
    float2 r;
    r.x = __uint_as_float(g << 16);
    r.y = __uint_as_float(g & 0xffff0000u);
    return r;
}

__global__ __launch_bounds__(256) void spmm_gather(
    const int* __restrict__ row_ptr, const int2* __restrict__ edges,
    const unsigned short* __restrict__ x, unsigned short* __restrict__ y,
    int nrows) {
    int gid = blockIdx.x * 256 + threadIdx.x;
    int row = gid >> 5;
    int lane = threadIdx.x & 31;
    if (row >= nrows) return;
    int beg = row_ptr[row], end = row_ptr[row + 1];
    float rx = 0.f, ry = 0.f;
    int k = beg;
    for (; k + 7 < end; k += 8) {
        int2 e[8];
        unsigned g[8];
#pragma unroll
        for (int j = 0; j < 8; ++j) e[j] = edges[k + j];
#pragma unroll
        for (int j = 0; j < 8; ++j)
            g[j] = *(const unsigned*)(x + ((size_t)e[j].x << 6) + lane * 2);
#pragma unroll
        for (int j = 0; j < 8; ++j) {
            float2 f = bf2_to_f2(g[j]);
            float v = __int_as_float(e[j].y);
            rx = fmaf(v, f.x, rx);
            ry = fmaf(v, f.y, ry);
        }
    }
    for (; k + 3 < end; k += 4) {
        int2 e[4];
        unsigned g[4];
#pragma unroll
        for (int j = 0; j < 4; ++j) e[j] = edges[k + j];
#pragma unroll
        for (int j = 0; j < 4; ++j)
            g[j] = *(const unsigned*)(x + ((size_t)e[j].x << 6) + lane * 2);
#pragma unroll
        for (int j = 0; j < 4; ++j) {
            float2 f = bf2_to_f2(g[j]);
            float v = __int_as_float(e[j].y);
            rx = fmaf(v, f.x, rx);
            ry = fmaf(v, f.y, ry);
        }
    }
    for (; k < end; ++k) {
        int2 e = edges[k];
        unsigned g = *(const unsigned*)(x + ((size_t)e.x << 6) + lane * 2);
        float2 f = bf2_to_f2(g);
        float v = __int_as_float(e.y);
        rx = fmaf(v, f.x, rx);
        ry = fmaf(v, f.y, ry);
    }
    __hip_bfloat162 pk = __float22bfloat162_rn(make_float2(rx, ry));
    *(unsigned*)(y + ((size_t)row << 6) + lane * 2) =
        *reinterpret_cast<unsigned*>(&pk);
}

// ---------------------------------------------------------------------------
// Fused classifier: Z = log_softmax((node_emb + y1 + y2 + y3)/4 @ W + b)
// W and bias accessed with wave-uniform compile-time indices -> scalar loads
// (no LDS, no per-FMA ds_read). Only z[50] accumulators live; x streamed.
// ---------------------------------------------------------------------------
__global__ __launch_bounds__(256) void classify(
    const float* __restrict__ node_emb, const unsigned short* __restrict__ y1,
    const unsigned short* __restrict__ y2,
    const unsigned short* __restrict__ y3, const float* __restrict__ W,
    const float* __restrict__ bias, float* __restrict__ Z) {
    int row = blockIdx.x * 256 + threadIdx.x;
    if (row >= N_NODES) return;
    const float4* np =
        reinterpret_cast<const float4*>(node_emb + (size_t)row * DIM);
    const unsigned* p1 = (const unsigned*)(y1 + ((size_t)row << 6));
    const unsigned* p2 = (const unsigned*)(y2 + ((size_t)row << 6));
    const unsigned* p3 = (const unsigned*)(y3 + ((size_t)row << 6));
    float z[NCLASS];
#pragma unroll
    for (int c = 0; c < NCLASS; ++c) z[c] = bias[c];
#pragma unroll
    for (int i = 0; i < DIM / 4; ++i) {
        float4 f = np[i];
        float2 a0 = bf2_to_f2(p1[2 * i]), a1 = bf2_to_f2(p1[2 * i + 1]);
        float2 c0 = bf2_to_f2(p2[2 * i]), c1 = bf2_to_f2(p2[2 * i + 1]);
        float2 d0 = bf2_to_f2(p3[2 * i]), d1 = bf2_to_f2(p3[2 * i + 1]);
        float xk0 = (f.x + a0.x + c0.x + d0.x) * 0.25f;
        float xk1 = (f.y + a0.y + c0.y + d0.y) * 0.25f;
        float xk2 = (f.z + a1.x + c1.x + d1.x) * 0.25f;
        float xk3 = (f.w + a1.y + c1.y + d1.y) * 0.25f;
#pragma unroll
        for (int c = 0; c < NCLASS; ++c) {
            z[c] = fmaf(xk0, W[(4 * i + 0) * NCLASS + c], z[c]);
            z[c] = fmaf(xk1, W[(4 * i + 1) * NCLASS + c], z[c]);
            z[c] = fmaf(xk2, W[(4 * i + 2) * NCLASS + c], z[c]);
            z[c] = fmaf(xk3, W[(4 * i + 3) * NCLASS + c], z[c]);
        }
    }
    float m = z[0];
#pragma unroll
    for (int c = 1; c < NCLASS; ++c) m = fmaxf(m, z[c]);
    float s = 0.f;
#pragma unroll
    for (int c = 0; c < NCLASS; ++c) s += __expf(z[c] - m);
    float ls = m + __logf(s);
    float* zp = Z + (size_t)row * NCLASS;
#pragma unroll
    for (int c = 0; c < NCLASS; ++c) zp[c] = z[c] - ls;
}

extern "C" void kernel_launch(void* const* d_in, const int* in_sizes, int n_in,
                              void* d_out, int out_size, void* d_ws, size_t ws_size,
                              hipStream_t stream) {
    const float* node_emb = (const float*)d_in[0];
    const float* hyper_emb = (const float*)d_in[1];
    const float* W = (const float*)d_in[2];
    const float* b = (const float*)d_in[3];
    const float* vals = (const float*)d_in[4];
    const int* rows = (const int*)d_in[5];
    const int* cols = (const int*)d_in[6];
    float* Z = (float*)d_out;

    const size_t BUFB = (size_t)N_TOTAL * DIM * 2;  // 25.6 MB (bf16)
    const size_t EDG = (size_t)NNZ * 8;             // 25.6 MB (int2)

    char* w = (char*)d_ws;
    unsigned short* xb = (unsigned short*)w;  w += BUFB;
    unsigned short* y1 = (unsigned short*)w;  w += BUFB;
    unsigned short* y2 = (unsigned short*)w;  w += BUFB;
    unsigned short* y3 = (unsigned short*)w;  w += BUFB;
    int2* edges = (int2*)w;                   w += EDG;
    int* row_ptr = (int*)w;                   w += (size_t)(N_TOTAL + 1) * 4;
    int* bcnt = (int*)w;                      w += 2048;
    int* boff = (int*)w;                      w += 2048;
    int* bcur = (int*)w;
    // recs aliases y2+y3 (51.2 MB >= 25.6 MB); recs is dead before pass 2.
    int2* recs = (int2*)y2;

    // ---- Bucketed CSR build ----
    hipMemsetAsync(bcnt, 0, NBUK * 4, stream);
    const int bin_blocks = (NNZ + EB - 1) / EB;  // 391
    bucket_hist<<<bin_blocks, 256, 0, stream>>>(rows, bcnt);
    bucket_scan<<<1, 512, 0, stream>>>(bcnt, boff, bcur);
    bin_edges<<<bin_blocks, 256, 0, stream>>>(rows, cols, vals, bcur, recs);
    build_csr<<<NBUK, 256, 0, stream>>>(boff, recs, row_ptr, edges);

    // ---- Build bf16 all_emb ----
    const int cvt_blocks = (int)(((size_t)N_TOTAL * DIM / 4 + 255) / 256);
    build_x_bf16<<<cvt_blocks, 256, 0, stream>>>(node_emb, hyper_emb,
                                                 (__hip_bfloat162*)xb);

    const int out_blocks = (N_NODES + 255) / 256;
    const int full_blocks = (N_TOTAL * 32 + 255) / 256;
    const int node_blocks = (N_NODES * 32 + 255) / 256;

    // L1: y1 = A x
    spmm_gather<<<full_blocks, 256, 0, stream>>>(row_ptr, edges, xb, y1,
                                                 N_TOTAL);
    // L2: y2 = A y1
    spmm_gather<<<full_blocks, 256, 0, stream>>>(row_ptr, edges, y1, y2,
                                                 N_TOTAL);
    // L3: y3 = A y2 (node rows only)
    spmm_gather<<<node_blocks, 256, 0, stream>>>(row_ptr, edges, y2, y3,
                                                 N_NODES);
    classify<<<out_blocks, 256, 0, stream>>>(node_emb, y1, y2, y3, W, b, Z);
}